// Round 4
// baseline (454.559 us; speedup 1.0000x reference)
//
#include <hip/hip_runtime.h>
#include <hip/hip_bf16.h>

// ---- problem constants (from setup_inputs) ----
#define B_   2
#define T_   4160
#define D_   1024
#define H_   16
#define KVH_ 4
#define HD_  64
#define UPD  2048          // update_start
#define NU   2112          // n_update = T - UPD
#define MQ   (B_*NU)       // 4224 rows of updated tokens
#define MT   (B_*T_)       // 8320 rows total

typedef unsigned short u16;
typedef unsigned int u32;
typedef __attribute__((ext_vector_type(8))) short bf16x8;
typedef __attribute__((ext_vector_type(4))) float f32x4;
typedef __attribute__((ext_vector_type(4))) unsigned short u16x4;

__device__ __forceinline__ float bf2f(u16 u){ return __uint_as_float(((unsigned)u)<<16); }
__device__ __forceinline__ u16 f2bf(float f){
  unsigned u = __float_as_uint(f);
  u += 0x7FFF + ((u>>16)&1);           // RNE
  return (u16)(u>>16);
}

// async global->LDS, 16B per lane; lds dst is wave-uniform base (+lane*16 by HW)
__device__ __forceinline__ void gll16(const void* g, void* l){
  __builtin_amdgcn_global_load_lds((const __attribute__((address_space(1))) char*)g,
                                   (__attribute__((address_space(3))) char*)l, 16, 0, 0);
}

// counted vmcnt wait (keeps newer loads in flight across barriers)
template<int N> __device__ __forceinline__ void wait_vm(){
  if constexpr(N==0) asm volatile("s_waitcnt vmcnt(0)" ::: "memory");
  else if constexpr(N==3) asm volatile("s_waitcnt vmcnt(3)" ::: "memory");
  else if constexpr(N==4) asm volatile("s_waitcnt vmcnt(4)" ::: "memory");
}

// ---------------- fused weight casts: f32 -> bf16 ----------------
// segments (blocks of 1024 elems): Wq 1024 | Wk 256 | Wv 256 | Wo 1024 | Wfc 4096 | Wproj 4096
__global__ void cast_all(const float* __restrict__ s0, const float* __restrict__ s1,
                         const float* __restrict__ s2, const float* __restrict__ s3,
                         const float* __restrict__ s4, const float* __restrict__ s5,
                         u16* __restrict__ d0, u16* __restrict__ d1, u16* __restrict__ d2,
                         u16* __restrict__ d3, u16* __restrict__ d4, u16* __restrict__ d5){
  int blk = blockIdx.x;
  const float* s; u16* d; int base;
  if      (blk < 1024){ s=s0; d=d0; base=blk; }
  else if (blk < 1280){ s=s1; d=d1; base=blk-1024; }
  else if (blk < 1536){ s=s2; d=d2; base=blk-1280; }
  else if (blk < 2560){ s=s3; d=d3; base=blk-1536; }
  else if (blk < 6656){ s=s4; d=d4; base=blk-2560; }
  else                { s=s5; d=d5; base=blk-6656; }
  int i = base*256 + threadIdx.x;       // float4 index
  float4 v = ((const float4*)s)[i];
  u16x4 u; u.x=f2bf(v.x); u.y=f2bf(v.y); u.z=f2bf(v.z); u.w=f2bf(v.w);
  ((u16x4*)d)[i] = u;
}

// ---------------- RMSNorm (one 256-thread block per row of 1024) ----------------
__global__ void rmsnorm_kernel(const float* __restrict__ in, u16* __restrict__ obf,
                               float* __restrict__ copy_out, int withcopy){
  int row = blockIdx.x;
  int t = threadIdx.x;
  const float* xr = in + (size_t)row*D_;
  float4 v = ((const float4*)xr)[t];
  float ss = v.x*v.x + v.y*v.y + v.z*v.z + v.w*v.w;
  #pragma unroll
  for (int o=32;o;o>>=1) ss += __shfl_xor(ss, o);
  __shared__ float red[4];
  if ((t&63)==0) red[t>>6] = ss;
  __syncthreads();
  float tot = red[0]+red[1]+red[2]+red[3];
  float sc = rsqrtf(tot*(1.0f/D_) + 1e-6f);
  u16x4 o4; o4.x=f2bf(v.x*sc); o4.y=f2bf(v.y*sc); o4.z=f2bf(v.z*sc); o4.w=f2bf(v.w*sc);
  ((u16x4*)(obf + (size_t)row*D_))[t] = o4;
  if (withcopy && (row % T_) < UPD)
    ((float4*)(copy_out + (size_t)row*D_))[t] = v;
}

// ---------------- L2-normalize contiguous 64-element vectors (×scale) ----------------
__global__ void l2norm_kernel(u16* __restrict__ buf, int nvec, float scale){
  int vid = blockIdx.x*4 + (threadIdx.x>>6);
  int ln = threadIdx.x & 63;
  if (vid >= nvec) return;
  u16* p = buf + (size_t)vid*64 + ln;
  float x = bf2f(*p);
  float ss = x*x;
  #pragma unroll
  for (int o=32;o;o>>=1) ss += __shfl_xor(ss, o);
  float n = sqrtf(ss);
  n = (n < 1e-12f) ? 1e-12f : n;
  *p = f2bf(x * scale / n);
}

// ---------------- bf16 GEMM: C[M,N] = A[M,K] * B[N,K]^T ----------------
// BM=128, BN in {64,128}. BN=128: 4 waves 2x2, wave=64x64, acc[4][4].
//                          BN=64 : 4 waves 4x1, wave=32x64, acc[2][4].
// BK=32, 16x16x32 MFMA. Triple-buffered LDS + counted vmcnt (T4): single raw
// s_barrier per K-step, next tile's global_load_lds stays in flight across it.
// LDS chunk swizzle: physical chunk = row*4 + (c ^ (row&3)) (source pre-swizzled,
// reads XOR-matched) -> frag ds_read_b128 conflict-free (was 8-way).
// EPI: 0=store bf16   1=softcap-tanh + x residual -> fp32 x_new
//      2=relu^2 -> bf16   3=x_new residual -> fp32 out (row-remapped)
//      5=merged KV: cols<256 -> kB bf16 ; cols>=256 -> vT transposed store
// AMAP: 0 identity; 1: A row r -> (r/NU)*T_ + UPD + r%NU  (x_upd slice of x_norm)
template<int EPI, int AMAP, int BN>
__global__ __launch_bounds__(256) void gemm_bt(
    const u16* __restrict__ A, const u16* __restrict__ Bw, void* __restrict__ C,
    void* __restrict__ aux, int M, int N, int K)
{
  constexpr int MI = (BN==128) ? 4 : 2;    // 16-row repeats per wave
  constexpr int NB = BN/64;                // B-chunks per thread per stage
  __shared__ alignas(16) u16 sA[3][4096];  // [128][32] chunk-swizzled
  __shared__ alignas(16) u16 sB[3][BN*32];
  // XCD swizzle: each XCD gets a contiguous chunk of row-major tile space
  unsigned nwg = gridDim.x*gridDim.y;
  unsigned flat = blockIdx.y*gridDim.x + blockIdx.x;
  unsigned nf = (flat&7)*(nwg>>3) + (flat>>3);
  int m0 = (int)(nf / gridDim.x) * 128;
  int n0 = (int)(nf % gridDim.x) * BN;
  int tid = threadIdx.x;
  int wv = tid>>6, ln = tid&63;
  int wr = (BN==128) ? (wv>>1) : wv;
  int wc = (BN==128) ? (wv&1)  : 0;
  int lr = ln&15, lg = ln>>4;

  // staging source pointers (chunk-swizzled) + LDS dest offsets, hoisted
  const char* pA[2]; int dA[2];
  #pragma unroll
  for (int c=0;c<2;c++){
    int ci = c*256 + tid;
    int row = ci>>2, csw = (ci&3) ^ (row&3);
    int arow = m0 + row;
    if (AMAP==1) arow = (arow/NU)*T_ + UPD + (arow%NU);
    pA[c] = (const char*)A + ((size_t)arow*K + csw*8)*2;
    dA[c] = (c*256 + wv*64)*16;
  }
  const char* pB[NB]; int dB[NB];
  #pragma unroll
  for (int c=0;c<NB;c++){
    int ci = c*256 + tid;
    int row = ci>>2, csw = (ci&3) ^ (row&3);
    pB[c] = (const char*)Bw + ((size_t)(n0+row)*K + csw*8)*2;
    dB[c] = (c*256 + wv*64)*16;
  }

  auto stage = [&](int bu, int kt){
    #pragma unroll
    for (int c=0;c<2;c++)  gll16(pA[c] + kt*64, (char*)sA[bu] + dA[c]);
    #pragma unroll
    for (int c=0;c<NB;c++) gll16(pB[c] + kt*64, (char*)sB[bu] + dB[c]);
  };

  f32x4 acc[MI][4] = {};
  int nk = K>>5;
  stage(0,0); stage(1,1);
  for (int t=0; t<nk; ++t){
    int bu = t%3;
    if (t+1<nk) wait_vm<2+NB>(); else wait_vm<0>();
    __builtin_amdgcn_s_barrier();
    __builtin_amdgcn_sched_barrier(0);
    if (t+2<nk) stage((t+2)%3, t+2);
    bf16x8 af[MI], bfr[4];
    #pragma unroll
    for (int i=0;i<MI;i++){
      int row = wr*(MI*16) + i*16 + lr;
      af[i] = *(const bf16x8*)&sA[bu][row*32 + (lg ^ (lr&3))*8];
    }
    #pragma unroll
    for (int j=0;j<4;j++){
      int row = wc*64 + j*16 + lr;
      bfr[j] = *(const bf16x8*)&sB[bu][row*32 + (lg ^ (lr&3))*8];
    }
    #pragma unroll
    for (int i=0;i<MI;i++)
      #pragma unroll
      for (int j=0;j<4;j++)
        acc[i][j] = __builtin_amdgcn_mfma_f32_16x16x32_bf16(af[i], bfr[j], acc[i][j], 0,0,0);
  }
  #pragma unroll
  for (int i=0;i<MI;i++)
    #pragma unroll
    for (int j=0;j<4;j++){
      int grow0 = m0 + wr*(MI*16) + i*16 + lg*4;
      int gcol  = n0 + wc*64 + j*16 + lr;
      if (EPI==5){
        if (gcol < 256){
          #pragma unroll
          for (int r=0;r<4;r++)
            ((u16*)C)[(size_t)(grow0+r)*256 + gcol] = f2bf(acc[i][j][r]);
        } else {
          int bb = grow0 / T_;              // grow0 mult of 4, never crosses batch
          int t  = grow0 - bb*T_;
          int kvh = (gcol>>6)&3, d = gcol&63;
          u16x4 pk;
          #pragma unroll
          for (int r=0;r<4;r++) pk[r] = f2bf(acc[i][j][r]);
          *(u16x4*)((u16*)aux + ((size_t)((bb*KVH_+kvh)*64 + d))*T_ + t) = pk;
        }
      } else {
        #pragma unroll
        for (int r=0;r<4;r++){
          int grow = grow0 + r;
          float cv = acc[i][j][r];
          if (EPI==0){
            ((u16*)C)[(size_t)grow*N + gcol] = f2bf(cv);
          } else if (EPI==1){
            int b = grow/NU, t = grow - b*NU;
            float e = __expf(cv*(2.0f/15.0f));
            float val = 15.f*(e-1.f)/(e+1.f) + ((const float*)aux)[((size_t)(b*T_ + UPD + t))*D_ + gcol];
            ((float*)C)[(size_t)grow*N + gcol] = val;
          } else if (EPI==2){
            float rr = cv>0.f ? cv : 0.f;
            ((u16*)C)[(size_t)grow*N + gcol] = f2bf(rr*rr);
          } else {
            int b = grow/NU, t = grow - b*NU;
            float val = ((const float*)aux)[(size_t)grow*N + gcol] + cv;
            ((float*)C)[((size_t)(b*T_ + UPD + t))*D_ + gcol] = val;
          }
        }
      }
    }
}

// ---------------- attention softmax+pack helper ----------------
// Swapped S^T layout: lane (lg,lr) holds S[q=qi*16+lr][k=k2*16+lg*4+r].
// k pre-scaled by 1/(8 ln2) -> P = exp2(s) directly.
// Pack 4 P values (k..k+3) -> one 8B LDS write at byte q*128 + ((k*2)^((q&7)<<4)).
template<bool DIAG>
__device__ __forceinline__ void sm_pack(const f32x4 (&s)[2][4], char* spw,
                                        int lr, int lg, int ktb, int qbg){
  #pragma unroll
  for (int qi=0;qi<2;qi++)
    #pragma unroll
    for (int k2=0;k2<4;k2++){
      float p[4];
      #pragma unroll
      for (int r=0;r<4;r++){
        float pv = __builtin_amdgcn_exp2f(s[qi][k2][r]);
        if (DIAG){
          int kpos = ktb + k2*16 + lg*4 + r;
          int qpos = qbg + qi*16 + lr;
          if (kpos > qpos) pv = 0.f;
        }
        p[r] = pv;
      }
      __hip_bfloat162 w0 = __float22bfloat162_rn(float2{p[0],p[1]});
      __hip_bfloat162 w1 = __float22bfloat162_rn(float2{p[2],p[3]});
      uint2 wd; wd.x = *(u32*)&w0; wd.y = *(u32*)&w1;
      *(uint2*)(spw + (qi*16+lr)*128 + ((k2*32 + lg*8) ^ ((lr&7)<<4))) = wd;
    }
}

// ---------------- attention ----------------
// grid (66 qtiles of 32 rows, kh=4, b=2) = 528 blocks, 4 waves.
// Wave w = q-head kh*4+w, 32 q-rows; K/V tiles shared by all 4 heads.
// V pre-transposed in vT[b][kvh][d][t] by the KV GEMM -> staged via gll16.
// Triple-buffered K/V + counted vmcnt(4): one raw barrier per kv-tile,
// next tile's loads in flight across it. Swapped QK^T; diagonal-only mask;
// exp2 direct; P via cvt_pk + 8B swizzled LDS writes.
__global__ __launch_bounds__(256) void attn_kernel(
    const u16* __restrict__ qb, const u16* __restrict__ kb,
    const u16* __restrict__ vT, u16* __restrict__ ab)
{
  __shared__ alignas(16) u16 sK[3][64*64];
  __shared__ alignas(16) u16 sV[3][64*64];
  __shared__ alignas(16) u16 sP[4][32*64];
  unsigned flat = (blockIdx.z*4u + blockIdx.y)*66u + blockIdx.x;
  unsigned nf = (flat&7)*66u + (flat>>3);
  int qi_blk = 65 - (int)(nf % 66u);          // longest-first within XCD
  unsigned khb = nf / 66u;
  int kh = (int)(khb & 3), b = (int)(khb >> 2);
  int tid = threadIdx.x, wv = tid>>6, ln = tid&63;
  int lr = ln&15, lg = ln>>4;
  int h = kh*4 + wv;
  int qrow0 = qi_blk*32;
  int qbg = UPD + qrow0;
  char* spw = (char*)&sP[wv][0];

  bf16x8 qf[2][2];
  #pragma unroll
  for (int qi=0;qi<2;qi++){
    const u16* qp = qb + (size_t)(b*NU + qrow0 + qi*16 + lr)*D_ + h*HD_;
    qf[qi][0] = *(const bf16x8*)(qp + lg*8);
    qf[qi][1] = *(const bf16x8*)(qp + 32 + lg*8);
  }
  bf16x8 ones;
  #pragma unroll
  for (int i=0;i<8;i++) ones[i] = (short)0x3F80;

  f32x4 accO[2][4] = {};
  f32x4 accD[2] = {};

  // hoisted staging pointers
  const char* pK[2]; const char* pV[2]; int dst[2];
  #pragma unroll
  for (int cc=0; cc<2; ++cc){
    int ci = cc*256 + tid;
    int row = ci>>3, slotb = (ci&7)*16;
    int scolb = slotb ^ ((row&7)<<4);
    pK[cc] = (const char*)kb + ((size_t)(b*T_ + row)*256 + kh*HD_)*2 + scolb;
    pV[cc] = (const char*)vT + ((size_t)((b*KVH_+kh)*64 + row)*T_)*2 + scolb;
    dst[cc] = (cc*256 + wv*64)*16;
  }
  auto stage = [&](int bu, int kt){
    #pragma unroll
    for (int cc=0; cc<2; ++cc)
      gll16(pK[cc] + kt*32768, (char*)sK[bu] + dst[cc]);
    #pragma unroll
    for (int cc=0; cc<2; ++cc)
      gll16(pV[cc] + kt*128,   (char*)sV[bu] + dst[cc]);
  };

  int nkt = 33 + (qi_blk>>1);
  stage(0,0); stage(1,1);
  for (int kt=0; kt<nkt; ++kt){
    int bu = kt%3;
    if (kt+1<nkt) wait_vm<4>(); else wait_vm<0>();
    __builtin_amdgcn_s_barrier();
    __builtin_amdgcn_sched_barrier(0);
    if (kt+2<nkt) stage((kt+2)%3, kt+2);
    // --- S^T = K Q^T ---
    f32x4 s[2][4];
    #pragma unroll
    for (int qi=0;qi<2;qi++)
      #pragma unroll
      for (int k2=0;k2<4;k2++) s[qi][k2] = (f32x4){0.f,0.f,0.f,0.f};
    #pragma unroll
    for (int k2=0;k2<4;k2++){
      int row = k2*16 + lr;
      int sw = (row&7)<<4;
      bf16x8 k0 = *(const bf16x8*)((const char*)sK[bu] + row*128 + ((lg*16)^sw));
      bf16x8 k1 = *(const bf16x8*)((const char*)sK[bu] + row*128 + ((64+lg*16)^sw));
      #pragma unroll
      for (int qi=0;qi<2;qi++){
        s[qi][k2] = __builtin_amdgcn_mfma_f32_16x16x32_bf16(k0, qf[qi][0], s[qi][k2], 0,0,0);
        s[qi][k2] = __builtin_amdgcn_mfma_f32_16x16x32_bf16(k1, qf[qi][1], s[qi][k2], 0,0,0);
      }
    }
    // --- exp2 -> packed bf16 P in LDS (mask only on diagonal tile) ---
    if (kt+1 < nkt) sm_pack<false>(s, spw, lr, lg, kt*64, qbg);
    else            sm_pack<true >(s, spw, lr, lg, kt*64, qbg);
    bf16x8 pf[2][2];
    #pragma unroll
    for (int qi=0;qi<2;qi++)
      #pragma unroll
      for (int hf=0;hf<2;hf++)
        pf[qi][hf] = *(const bf16x8*)(spw + (qi*16+lr)*128 + ((hf*64 + lg*16) ^ ((lr&7)<<4)));
    // --- O += P V^T, den += P 1 ---
    #pragma unroll
    for (int dt=0; dt<4; ++dt){
      int row = dt*16 + lr;
      int sw = (row&7)<<4;
      bf16x8 v0 = *(const bf16x8*)((const char*)sV[bu] + row*128 + ((lg*16)^sw));
      bf16x8 v1 = *(const bf16x8*)((const char*)sV[bu] + row*128 + ((64+lg*16)^sw));
      #pragma unroll
      for (int qi=0;qi<2;qi++){
        accO[qi][dt] = __builtin_amdgcn_mfma_f32_16x16x32_bf16(pf[qi][0], v0, accO[qi][dt], 0,0,0);
        accO[qi][dt] = __builtin_amdgcn_mfma_f32_16x16x32_bf16(pf[qi][1], v1, accO[qi][dt], 0,0,0);
      }
    }
    #pragma unroll
    for (int qi=0;qi<2;qi++){
      accD[qi] = __builtin_amdgcn_mfma_f32_16x16x32_bf16(pf[qi][0], ones, accD[qi], 0,0,0);
      accD[qi] = __builtin_amdgcn_mfma_f32_16x16x32_bf16(pf[qi][1], ones, accD[qi], 0,0,0);
    }
  }
  #pragma unroll
  for (int qi=0;qi<2;qi++)
    #pragma unroll
    for (int dt=0; dt<4; ++dt)
      #pragma unroll
      for (int r=0;r<4;r++){
        float val = accO[qi][dt][r] / accD[qi][r];
        size_t row = (size_t)(b*NU + qrow0 + qi*16 + lg*4 + r);
        ab[row*D_ + h*HD_ + dt*16 + lr] = f2bf(val);
      }
}

// ---------------- launch ----------------
extern "C" void kernel_launch(void* const* d_in, const int* in_sizes, int n_in,
                              void* d_out, int out_size, void* d_ws, size_t ws_size,
                              hipStream_t stream)
{
  const float* x     = (const float*)d_in[0];
  const float* Wq    = (const float*)d_in[1];
  const float* Wk    = (const float*)d_in[2];
  const float* Wv    = (const float*)d_in[3];
  const float* Wo    = (const float*)d_in[4];
  const float* Wfc   = (const float*)d_in[5];
  const float* Wproj = (const float*)d_in[6];
  float* out = (float*)d_out;

  char* ws = (char*)d_ws;
  size_t off = 0;
  auto alloc = [&](size_t bytes)->char*{ char* p = ws + off; off += (bytes + 255) & ~(size_t)255; return p; };
  u16* wqb  = (u16*)alloc((size_t)D_*D_*2);
  u16* wkvb = (u16*)alloc((size_t)512*D_*2);    // rows 0..255 = Wk, 256..511 = Wv
  u16* wob  = (u16*)alloc((size_t)D_*D_*2);
  u16* wfcb = (u16*)alloc((size_t)4096*D_*2);
  u16* wpb  = (u16*)alloc((size_t)D_*4096*2);
  u16* xn   = (u16*)alloc((size_t)MT*D_*2);
  u16* qB   = (u16*)alloc((size_t)MQ*D_*2);
  u16* kB   = (u16*)alloc((size_t)MT*256*2);
  u16* vTb  = (u16*)alloc((size_t)B_*KVH_*64*T_*2);   // [b][kvh][d][t]
  u16* aB   = (u16*)alloc((size_t)MQ*D_*2);
  float* xnew = (float*)alloc((size_t)MQ*D_*4);
  u16* xn2  = (u16*)alloc((size_t)MQ*D_*2);
  u16* hB   = (u16*)alloc((size_t)MQ*4096*2);
  (void)ws_size; (void)in_sizes; (void)n_in; (void)out_size;

  // all weights -> bf16, one kernel
  cast_all<<<10752, 256, 0, stream>>>(Wq, Wk, Wv, Wo, Wfc, Wproj,
                                      wqb, wkvb, wkvb + (size_t)256*D_, wob, wfcb, wpb);

  // x_norm (bf16) + passthrough copy of prefix rows to out
  rmsnorm_kernel<<<MT, 256, 0, stream>>>(x, xn, out, 1);

  // projections: Q (BN=64), merged KV (BN=64; K -> kB rows, V -> vT transposed)
  gemm_bt<0,1,64><<<dim3(16,33), 256, 0, stream>>>(xn, wqb, qB, nullptr, MQ, D_,  D_);
  gemm_bt<5,0,64><<<dim3(8,65),  256, 0, stream>>>(xn, wkvb, kB, vTb, MT, 512, D_);

  // L2 normalize q; k also pre-scaled by 1/(8 ln2) so attn uses exp2 directly
  l2norm_kernel<<<(MQ*H_)/4, 256, 0, stream>>>(qB, MQ*H_, 1.0f);
  l2norm_kernel<<<(MT*KVH_)/4, 256, 0, stream>>>(kB, MT*KVH_, 0.18033688f);

  // attention
  attn_kernel<<<dim3(66,4,2), 256, 0, stream>>>(qB, kB, vTb, aB);

  // out-proj + softcap + residual -> x_new (fp32)
  gemm_bt<1,0,64><<<dim3(16,33), 256, 0, stream>>>(aB, wob, xnew, (void*)x, MQ, D_, D_);

  // MLP
  rmsnorm_kernel<<<MQ, 256, 0, stream>>>(xnew, xn2, nullptr, 0);
  gemm_bt<2,0,128><<<dim3(32,33), 256, 0, stream>>>(xn2, wfcb, hB, nullptr, MQ, 4096, D_);
  gemm_bt<3,0,64><<<dim3(16,33), 256, 0, stream>>>(hB, wpb, out, xnew, MQ, D_, 4096);
}